// Round 3
// baseline (727.823 us; speedup 1.0000x reference)
//
#include <hip/hip_runtime.h>

#define NB 64
#define NS 2048
#define ND 64
#define KSTEP 64
#define NIT (NS / KSTEP)  // 32

typedef __bf16 bf16x8 __attribute__((ext_vector_type(8)));
typedef float f32x4 __attribute__((ext_vector_type(4)));
typedef float f32x16 __attribute__((ext_vector_type(16)));
typedef unsigned int u32;
typedef u32 u32x4 __attribute__((ext_vector_type(4)));

__device__ __forceinline__ unsigned short f2bs(float x) {
  __bf16 h = (__bf16)x;
  return __builtin_bit_cast(unsigned short, h);
}

__device__ __forceinline__ bf16x8 cvt8(f32x4 a, f32x4 b) {
  bf16x8 r;
  r[0] = (__bf16)a[0]; r[1] = (__bf16)a[1]; r[2] = (__bf16)a[2]; r[3] = (__bf16)a[3];
  r[4] = (__bf16)b[0]; r[5] = (__bf16)b[1]; r[6] = (__bf16)b[2]; r[7] = (__bf16)b[3];
  return r;
}

// mfma_f32_32x32x16_bf16 layout facts:
//   A: lane holds A[row = l&31][k-slot], B: B[k-slot][col = l&31] (mirrored
//   k-maps, so any consistent A/B slot<->k bijection computes the dot right).
//   D: col = l&31, row = (reg&3) + 8*(reg>>2) + 4*(l>>5)   [m74/m101 verified]
// QK^T: A=K, B=Q  ->  lane owns W[q = l&31][k = 4h + (j&3) + 8*(j>>2)].
// PV:   A=V^T staged with k permuted by kappa(h,s) = 4h + (s&3) + 8*(s>>2),
//       B=W straight from the QK^T D registers (no LDS round trip).
__global__ __launch_bounds__(256, 3) void DotProductAttention_22436909154804_kernel(
    const float* __restrict__ Q, const float* __restrict__ K,
    const float* __restrict__ V, const int* __restrict__ M,
    float* __restrict__ ctx, float* __restrict__ wts) {
  __shared__ __attribute__((aligned(16))) unsigned short Kt[2][64][68];  // [k][d]
  __shared__ __attribute__((aligned(16))) unsigned short Vt[2][64][68];  // [d][perm k]

  const int tid  = threadIdx.x;
  const int lane = tid & 63;
  const int w    = tid >> 6;
  const int q    = lane & 31;
  const int h    = lane >> 5;

  // XCD-bijective swizzle (1024 = 8*128): same-batch blocks share an XCD.
  const int bid = blockIdx.x;
  const int vb  = (bid & 7) * 128 + (bid >> 3);
  const int b   = vb >> 4;
  const int qt  = vb & 15;
  const int q0  = qt * 128 + w * 32;
  const size_t bq = (size_t)b * NS;

  // Q B-frags: chunk c covers d = 16c + 8h + s
  const float* qp = Q + (bq + q0 + q) * ND + 8 * h;
  bf16x8 qf[4];
#pragma unroll
  for (int c = 0; c < 4; ++c)
    qf[c] = cvt8(*(const f32x4*)(qp + 16 * c), *(const f32x4*)(qp + 16 * c + 4));

  const float* Kb = K + bq * ND;
  const float* Vb = V + bq * ND;
  const int*   Mr = M + (size_t)(q0 + q) * NS;  // mask shared across batches

  // staging maps
  const int skr = tid >> 2;        // K row 0..63
  const int skd = (tid & 3) * 16;  // K d-quarter
  const int sva = tid >> 3;        // V k-pair 0..31
  const int svd = (tid & 7) * 8;   // V d base
  const int c16 = (2 * sva) & 15;
  const int vcol = 16 * ((2 * sva) >> 4) + 8 * ((c16 >> 2) & 1) + (c16 & 3) + 4 * ((c16 >> 3) & 1);

  f32x4 kst[4], vst[4];
  auto issueK = [&](int kb) {
    const float* p = Kb + (size_t)(kb + skr) * ND + skd;
    kst[0] = *(const f32x4*)p;       kst[1] = *(const f32x4*)(p + 4);
    kst[2] = *(const f32x4*)(p + 8); kst[3] = *(const f32x4*)(p + 12);
  };
  auto writeK = [&](int buf) {
    *(bf16x8*)&Kt[buf][skr][skd]     = cvt8(kst[0], kst[1]);
    *(bf16x8*)&Kt[buf][skr][skd + 8] = cvt8(kst[2], kst[3]);
  };
  auto issueV = [&](int kb) {
    const float* p = Vb + (size_t)(kb + 2 * sva) * ND + svd;
    vst[0] = *(const f32x4*)p;        vst[1] = *(const f32x4*)(p + 4);
    vst[2] = *(const f32x4*)(p + ND); vst[3] = *(const f32x4*)(p + ND + 4);
  };
  auto writeV = [&](int buf) {
#pragma unroll
    for (int j = 0; j < 8; ++j) {
      float lo = (j < 4) ? vst[0][j] : vst[1][j - 4];
      float hi = (j < 4) ? vst[2][j] : vst[3][j - 4];
      *(u32*)&Vt[buf][svd + j][vcol] = (u32)f2bs(lo) | ((u32)f2bs(hi) << 16);
    }
  };

  // ---------------- Phase 1: row sums ----------------
  float rs = 0.f;
  issueK(0);
  writeK(0);
  __syncthreads();
  for (int it = 0; it < NIT; ++it) {
    const int cur = it & 1, kb = it * KSTEP;
    if (it + 1 < NIT) issueK(kb + KSTEP);
#pragma unroll
    for (int kt = 0; kt < 2; ++kt) {
      f32x16 d = {};
#pragma unroll
      for (int c = 0; c < 4; ++c) {
        bf16x8 a = *(const bf16x8*)&Kt[cur][kt * 32 + q][16 * c + 8 * h];
        d = __builtin_amdgcn_mfma_f32_32x32x16_bf16(a, qf[c], d, 0, 0, 0);
      }
#pragma unroll
      for (int quad = 0; quad < 4; ++quad) {
        const int4 mm = *(const int4*)(Mr + kb + kt * 32 + 8 * quad + 4 * h);
        rs += (mm.x ? __expf(d[4 * quad + 0] * 0.125f) : 0.f)
            + (mm.y ? __expf(d[4 * quad + 1] * 0.125f) : 0.f)
            + (mm.z ? __expf(d[4 * quad + 2] * 0.125f) : 0.f)
            + (mm.w ? __expf(d[4 * quad + 3] * 0.125f) : 0.f);
      }
    }
    if (it + 1 < NIT) writeK((it + 1) & 1);
    __syncthreads();
  }
  rs += __shfl_xor(rs, 32);
  const float inv = 1.f / rs;

  // ---------------- Phase 2: weights out + PV ----------------
  f32x16 acc[2] = {};
  issueK(0); issueV(0);
  writeK(0); writeV(0);
  __syncthreads();
  float* wrow = wts + (bq + q0 + q) * NS;
  for (int it = 0; it < NIT; ++it) {
    const int cur = it & 1, kb = it * KSTEP;
    if (it + 1 < NIT) { issueK(kb + KSTEP); issueV(kb + KSTEP); }
#pragma unroll
    for (int kt = 0; kt < 2; ++kt) {
      f32x16 d = {};
#pragma unroll
      for (int c = 0; c < 4; ++c) {
        bf16x8 a = *(const bf16x8*)&Kt[cur][kt * 32 + q][16 * c + 8 * h];
        d = __builtin_amdgcn_mfma_f32_32x32x16_bf16(a, qf[c], d, 0, 0, 0);
      }
      u32 wpk[8];
#pragma unroll
      for (int quad = 0; quad < 4; ++quad) {
        const int4 mm = *(const int4*)(Mr + kb + kt * 32 + 8 * quad + 4 * h);
        float w0 = mm.x ? __expf(d[4 * quad + 0] * 0.125f) * inv : 0.f;
        float w1 = mm.y ? __expf(d[4 * quad + 1] * 0.125f) * inv : 0.f;
        float w2 = mm.z ? __expf(d[4 * quad + 2] * 0.125f) * inv : 0.f;
        float w3 = mm.w ? __expf(d[4 * quad + 3] * 0.125f) * inv : 0.f;
        f32x4 wv = {w0, w1, w2, w3};
        *(f32x4*)(wrow + kb + kt * 32 + 8 * quad + 4 * h) = wv;
        wpk[2 * quad]     = (u32)f2bs(w0) | ((u32)f2bs(w1) << 16);
        wpk[2 * quad + 1] = (u32)f2bs(w2) | ((u32)f2bs(w3) << 16);
      }
#pragma unroll
      for (int cc = 0; cc < 2; ++cc) {
        u32x4 wu = {wpk[4 * cc + 0], wpk[4 * cc + 1], wpk[4 * cc + 2], wpk[4 * cc + 3]};
        bf16x8 wb = __builtin_bit_cast(bf16x8, wu);
#pragma unroll
        for (int dt = 0; dt < 2; ++dt) {
          bf16x8 va = *(const bf16x8*)&Vt[cur][dt * 32 + q][16 * (2 * kt + cc) + 8 * h];
          acc[dt] = __builtin_amdgcn_mfma_f32_32x32x16_bf16(va, wb, acc[dt], 0, 0, 0);
        }
      }
    }
    if (it + 1 < NIT) { writeK((it + 1) & 1); writeV((it + 1) & 1); }
    __syncthreads();
  }

  // ctx: lane q-row q0+q holds d = dt*32 + 4h + 8*quad + (reg&3)
  float* crow = ctx + (bq + q0 + q) * ND;
#pragma unroll
  for (int dt = 0; dt < 2; ++dt)
#pragma unroll
    for (int quad = 0; quad < 4; ++quad) {
      f32x4 vv = {acc[dt][4 * quad + 0], acc[dt][4 * quad + 1],
                  acc[dt][4 * quad + 2], acc[dt][4 * quad + 3]};
      *(f32x4*)(crow + dt * 32 + 8 * quad + 4 * h) = vv;
    }
}

extern "C" void kernel_launch(void* const* d_in, const int* in_sizes, int n_in,
                              void* d_out, int out_size, void* d_ws, size_t ws_size,
                              hipStream_t stream) {
  const float* Q = (const float*)d_in[0];
  const float* K = (const float*)d_in[1];
  const float* V = (const float*)d_in[2];
  const int*   M = (const int*)d_in[3];
  float* ctx = (float*)d_out;                         // [B,S,D]
  float* wts = (float*)d_out + (size_t)NB * NS * ND;  // [B,S,S]

  dim3 grid(NB * (NS / 128));  // 1024
  dim3 block(256);
  hipLaunchKernelGGL(DotProductAttention_22436909154804_kernel, grid, block, 0, stream,
                     Q, K, V, M, ctx, wts);
}